// Round 1
// baseline (99.464 us; speedup 1.0000x reference)
//
#include <hip/hip_runtime.h>
#include <stdint.h>

#define TT 128
#define BB 4096
#define HH 64
#define BC 16     // batch rows per block
#define SROW 72   // padded LDS row stride (bf16 elems): 144B rows, 16B aligned

typedef __attribute__((ext_vector_type(8))) short bf16x8;
typedef __attribute__((ext_vector_type(4))) float f32x4;

__device__ __forceinline__ short f2bf(float f) {
  uint32_t u = __builtin_bit_cast(uint32_t, f);
  u += 0x7fffu + ((u >> 16) & 1u);   // RNE
  return (short)(u >> 16);
}
__device__ __forceinline__ float sigm(float x) { return 1.0f / (1.0f + __expf(-x)); }
__device__ __forceinline__ float tanhf_fast(float x) {
  float e = __expf(2.0f * x);
  return 1.0f - 2.0f / (e + 1.0f);
}

__global__ __launch_bounds__(256) void gru_fused(
    const float* __restrict__ Hseq, const float* __restrict__ W_ih,
    const float* __restrict__ W_hh, const float* __restrict__ b_ih,
    const float* __restrict__ b_hh, const float* __restrict__ W_out,
    const float* __restrict__ b_out, float* __restrict__ out) {
  __shared__ __align__(16) short hsh[2][BC][SROW];  // bf16 h state, double buffered
  __shared__ float psum[4][BC];

  const int tid = threadIdx.x;
  const int w   = tid >> 6;    // wave 0..3 -> gate chunks {w, w+4, w+8} (r,z,n), j in [16w,16w+16)
  const int l   = tid & 63;
  const int llo = l & 15;      // batch col (B/D) or gate row (A)
  const int lhi = l >> 4;
  const int k0  = lhi * 8;
  const int bbase = blockIdx.x * BC;

  // ---- persistent W A-fragments (bf16), loaded once ----
  bf16x8 wih[3][2], whh[3][2];
#pragma unroll
  for (int c = 0; c < 3; ++c) {
    const int grow = (w + 4 * c) * 16 + llo;
#pragma unroll
    for (int hf = 0; hf < 2; ++hf) {
      const float* p = &W_ih[grow * 64 + hf * 32 + k0];
      const float* q = &W_hh[grow * 64 + hf * 32 + k0];
      bf16x8 a, b;
#pragma unroll
      for (int i = 0; i < 8; ++i) { a[i] = f2bf(p[i]); b[i] = f2bf(q[i]); }
      wih[c][hf] = a;
      whh[c][hf] = b;
    }
  }

  // ---- per-lane bias fragments (D rows j = 16w + lhi*4 + r) ----
  f32x4 biasR, biasZ, biasXN, biasHN;
#pragma unroll
  for (int r = 0; r < 4; ++r) {
    const int j = 16 * w + lhi * 4 + r;
    biasR[r]  = b_ih[j] + b_hh[j];
    biasZ[r]  = b_ih[64 + j] + b_hh[64 + j];
    biasXN[r] = b_ih[128 + j];
    biasHN[r] = b_hh[128 + j];
  }

  // zero h buffer 0 (h0 = 0)
  for (int i = tid; i < BC * SROW; i += 256) ((short*)hsh[0])[i] = 0;

  f32x4 hfp = {0.f, 0.f, 0.f, 0.f};  // fp32 h state, lane-local (batch llo, 4 j's)

  // x prefetch: 16 fp32/lane = Hseq[t][bbase+llo][k0+{0..7}] and [k0+32+{0..7}]
  f32x4 xq0, xq1, xq2, xq3;
  {
    const f32x4* p = (const f32x4*)(Hseq + (size_t)(bbase + llo) * HH + k0);
    xq0 = p[0]; xq1 = p[1]; xq2 = p[8]; xq3 = p[9];
  }

  __syncthreads();

  for (int t = 0; t < TT; ++t) {
    // convert prefetched x to B-frags (bf16)
    bf16x8 xb0, xb1;
#pragma unroll
    for (int i = 0; i < 4; ++i) {
      xb0[i]     = f2bf(xq0[i]);
      xb0[4 + i] = f2bf(xq1[i]);
      xb1[i]     = f2bf(xq2[i]);
      xb1[4 + i] = f2bf(xq3[i]);
    }
    // prefetch next step's x (clamped at the tail; result unused there)
    {
      const int tn = (t < TT - 1) ? t + 1 : t;
      const f32x4* p = (const f32x4*)(Hseq + ((size_t)tn * BB + bbase + llo) * HH + k0);
      xq0 = p[0]; xq1 = p[1]; xq2 = p[8]; xq3 = p[9];
    }
    // h B-frags from LDS (written by all waves last step)
    const int buf = t & 1;
    const bf16x8 hb0 = *(const bf16x8*)&hsh[buf][llo][k0];
    const bf16x8 hb1 = *(const bf16x8*)&hsh[buf][llo][k0 + 32];

    f32x4 aR = biasR, aZ = biasZ, aXN = biasXN, aHN = biasHN;
    aR  = __builtin_amdgcn_mfma_f32_16x16x32_bf16(wih[0][0], xb0, aR, 0, 0, 0);
    aR  = __builtin_amdgcn_mfma_f32_16x16x32_bf16(wih[0][1], xb1, aR, 0, 0, 0);
    aR  = __builtin_amdgcn_mfma_f32_16x16x32_bf16(whh[0][0], hb0, aR, 0, 0, 0);
    aR  = __builtin_amdgcn_mfma_f32_16x16x32_bf16(whh[0][1], hb1, aR, 0, 0, 0);
    aZ  = __builtin_amdgcn_mfma_f32_16x16x32_bf16(wih[1][0], xb0, aZ, 0, 0, 0);
    aZ  = __builtin_amdgcn_mfma_f32_16x16x32_bf16(wih[1][1], xb1, aZ, 0, 0, 0);
    aZ  = __builtin_amdgcn_mfma_f32_16x16x32_bf16(whh[1][0], hb0, aZ, 0, 0, 0);
    aZ  = __builtin_amdgcn_mfma_f32_16x16x32_bf16(whh[1][1], hb1, aZ, 0, 0, 0);
    aXN = __builtin_amdgcn_mfma_f32_16x16x32_bf16(wih[2][0], xb0, aXN, 0, 0, 0);
    aXN = __builtin_amdgcn_mfma_f32_16x16x32_bf16(wih[2][1], xb1, aXN, 0, 0, 0);
    aHN = __builtin_amdgcn_mfma_f32_16x16x32_bf16(whh[2][0], hb0, aHN, 0, 0, 0);
    aHN = __builtin_amdgcn_mfma_f32_16x16x32_bf16(whh[2][1], hb1, aHN, 0, 0, 0);

    // fp32 gate math + state update (lane-local)
#pragma unroll
    for (int r = 0; r < 4; ++r) {
      const float rr = sigm(aR[r]);
      const float zz = sigm(aZ[r]);
      const float nn = tanhf_fast(aXN[r] + rr * aHN[r]);
      hfp[r] = (1.0f - zz) * nn + zz * hfp[r];
    }
    // publish bf16 h to the other buffer: hsh[buf^1][llo][16w + lhi*4 .. +3]
    uint32_t p0 = (uint32_t)(uint16_t)f2bf(hfp[0]) | ((uint32_t)(uint16_t)f2bf(hfp[1]) << 16);
    uint32_t p1 = (uint32_t)(uint16_t)f2bf(hfp[2]) | ((uint32_t)(uint16_t)f2bf(hfp[3]) << 16);
    uint2 pk; pk.x = p0; pk.y = p1;
    *(uint2*)&hsh[buf ^ 1][llo][16 * w + lhi * 4] = pk;
    __syncthreads();
  }

  // ---- head: out[b] = h_last[b,:] . W_out + b_out ----
  float part = 0.f;
#pragma unroll
  for (int r = 0; r < 4; ++r) part += hfp[r] * W_out[16 * w + lhi * 4 + r];
  part += __shfl_xor(part, 16);
  part += __shfl_xor(part, 32);
  if (lhi == 0) psum[w][llo] = part;
  __syncthreads();
  if (tid < BC)
    out[bbase + tid] = psum[0][tid] + psum[1][tid] + psum[2][tid] + psum[3][tid] + b_out[0];
}

extern "C" void kernel_launch(void* const* d_in, const int* in_sizes, int n_in,
                              void* d_out, int out_size, void* d_ws, size_t ws_size,
                              hipStream_t stream) {
  (void)in_sizes; (void)n_in; (void)d_ws; (void)ws_size; (void)out_size;
  const float* Hseq  = (const float*)d_in[0];
  const float* W_ih  = (const float*)d_in[1];
  const float* W_hh  = (const float*)d_in[2];
  const float* b_ih  = (const float*)d_in[3];
  const float* b_hh  = (const float*)d_in[4];
  const float* W_out = (const float*)d_in[5];
  const float* b_out = (const float*)d_in[6];
  float* out = (float*)d_out;
  gru_fused<<<BB / BC, 256, 0, stream>>>(Hseq, W_ih, W_hh, b_ih, b_hh, W_out, b_out, out);
}

// Round 2
// 71.002 us; speedup vs baseline: 1.4009x; 1.4009x over previous
//
#include <hip/hip_runtime.h>
#include <stdint.h>

#define TT 128
#define BB 4096
#define HH 64
#define BC 16      // batch rows per block
#define XSTR 196   // xg LDS row stride (floats); 49 dwords -> conflict-light
#define HSTR 72    // h LDS row stride (bf16 shorts); 144B rows, 16B aligned

typedef __attribute__((ext_vector_type(8))) short bf16x8;
typedef __attribute__((ext_vector_type(4))) float f32x4;

static __device__ __forceinline__ short f2bf(float f) {  // RNE, one-time W convert
  uint32_t u = __builtin_bit_cast(uint32_t, f);
  u += 0x7fffu + ((u >> 16) & 1u);
  return (short)(u >> 16);
}
static __device__ __forceinline__ uint32_t cvtpk(float a, float b) {
  uint32_t r;
  asm("v_cvt_pk_bf16_f32 %0, %1, %2" : "=v"(r) : "v"(a), "v"(b));
  return r;  // lo16 = bf16(a), hi16 = bf16(b)
}
static __device__ __forceinline__ float rcpf(float x) { return __builtin_amdgcn_rcpf(x); }
static __device__ __forceinline__ float sigm(float x) { return rcpf(1.0f + __expf(-x)); }
static __device__ __forceinline__ float tanhf_fast(float x) {
  float e = __expf(2.0f * x);
  return 1.0f - 2.0f * rcpf(e + 1.0f);
}

__global__ __launch_bounds__(512) void gru_fused(
    const float* __restrict__ Hseq, const float* __restrict__ W_ih,
    const float* __restrict__ W_hh, const float* __restrict__ b_ih,
    const float* __restrict__ b_hh, const float* __restrict__ W_out,
    const float* __restrict__ b_out, float* __restrict__ out) {
  __shared__ __align__(16) short hsh[2][BC][HSTR];   // bf16 h state, double buffered
  __shared__ __align__(16) float xgsh[2][BC][XSTR];  // fp32 x-side gate preacts
  __shared__ float psum[4][BC];

  const int tid = threadIdx.x;
  const int w   = tid >> 6;     // 0..7; 0-3 consumers (recurrence), 4-7 producers (x GEMM)
  const int gw  = w & 3;        // gate-row chunk: j in [16gw, 16gw+16)
  const bool cons = (w < 4);
  const int l   = tid & 63;
  const int llo = l & 15;       // batch col (B/D frags) or gate row (A frag)
  const int lhi = l >> 4;
  const int k0  = lhi * 8;
  const int bbase = blockIdx.x * BC;

  // zero h buffer 0 (h0 = 0)
  for (int i = tid; i < BC * HSTR; i += 512) ((short*)hsh[0])[i] = 0;

  bf16x8 wa[3][2];                       // consumer: W_hh frags; producer: W_ih frags
  f32x4 biasHN = {0, 0, 0, 0};           // consumer only
  f32x4 biasPR = {0, 0, 0, 0}, biasPZ = {0, 0, 0, 0}, biasPN = {0, 0, 0, 0};  // producer
  f32x4 hfp = {0.f, 0.f, 0.f, 0.f};      // consumer fp32 h (batch llo, 4 j's)
  f32x4 xq0 = {0,0,0,0}, xq1 = {0,0,0,0}, xq2 = {0,0,0,0}, xq3 = {0,0,0,0};

  if (cons) {
#pragma unroll
    for (int c = 0; c < 3; ++c) {
      const int grow = 16 * gw + 64 * c + llo;
#pragma unroll
      for (int hf = 0; hf < 2; ++hf) {
        const float* q = &W_hh[grow * 64 + hf * 32 + k0];
        bf16x8 b;
#pragma unroll
        for (int i = 0; i < 8; ++i) b[i] = f2bf(q[i]);
        wa[c][hf] = b;
      }
    }
#pragma unroll
    for (int r = 0; r < 4; ++r) biasHN[r] = b_hh[128 + 16 * gw + lhi * 4 + r];
  } else {
#pragma unroll
    for (int c = 0; c < 3; ++c) {
      const int grow = 16 * gw + 64 * c + llo;
#pragma unroll
      for (int hf = 0; hf < 2; ++hf) {
        const float* p = &W_ih[grow * 64 + hf * 32 + k0];
        bf16x8 a;
#pragma unroll
        for (int i = 0; i < 8; ++i) a[i] = f2bf(p[i]);
        wa[c][hf] = a;
      }
    }
#pragma unroll
    for (int r = 0; r < 4; ++r) {
      const int j = 16 * gw + lhi * 4 + r;
      biasPR[r] = b_ih[j] + b_hh[j];
      biasPZ[r] = b_ih[64 + j] + b_hh[64 + j];
      biasPN[r] = b_ih[128 + j];
    }
    // load x[0]
    const f32x4* p = (const f32x4*)(Hseq + (size_t)(bbase + llo) * HH + k0);
    xq0 = p[0]; xq1 = p[1]; xq2 = p[8]; xq3 = p[9];
  }

  // producer pre-step: xg[0] into buffer 0, then prefetch x[1]
  if (!cons) {
    union { uint32_t u[4]; bf16x8 v; } c0, c1;
    c0.u[0] = cvtpk(xq0[0], xq0[1]); c0.u[1] = cvtpk(xq0[2], xq0[3]);
    c0.u[2] = cvtpk(xq1[0], xq1[1]); c0.u[3] = cvtpk(xq1[2], xq1[3]);
    c1.u[0] = cvtpk(xq2[0], xq2[1]); c1.u[1] = cvtpk(xq2[2], xq2[3]);
    c1.u[2] = cvtpk(xq3[0], xq3[1]); c1.u[3] = cvtpk(xq3[2], xq3[3]);
    f32x4 cR = biasPR, cZ = biasPZ, cN = biasPN;
    cR = __builtin_amdgcn_mfma_f32_16x16x32_bf16(wa[0][0], c0.v, cR, 0, 0, 0);
    cR = __builtin_amdgcn_mfma_f32_16x16x32_bf16(wa[0][1], c1.v, cR, 0, 0, 0);
    cZ = __builtin_amdgcn_mfma_f32_16x16x32_bf16(wa[1][0], c0.v, cZ, 0, 0, 0);
    cZ = __builtin_amdgcn_mfma_f32_16x16x32_bf16(wa[1][1], c1.v, cZ, 0, 0, 0);
    cN = __builtin_amdgcn_mfma_f32_16x16x32_bf16(wa[2][0], c0.v, cN, 0, 0, 0);
    cN = __builtin_amdgcn_mfma_f32_16x16x32_bf16(wa[2][1], c1.v, cN, 0, 0, 0);
    *(f32x4*)&xgsh[0][llo][16 * gw + lhi * 4]       = cR;
    *(f32x4*)&xgsh[0][llo][64 + 16 * gw + lhi * 4]  = cZ;
    *(f32x4*)&xgsh[0][llo][128 + 16 * gw + lhi * 4] = cN;
    const f32x4* p = (const f32x4*)(Hseq + ((size_t)BB + bbase + llo) * HH + k0);
    xq0 = p[0]; xq1 = p[1]; xq2 = p[8]; xq3 = p[9];
  }
  __syncthreads();

  for (int t = 0; t < TT; ++t) {
    const int buf = t & 1;
    if (cons) {
      // acc init from x-side preacts (fp32, both biases folded for r/z)
      f32x4 aR  = *(const f32x4*)&xgsh[buf][llo][16 * gw + lhi * 4];
      f32x4 aZ  = *(const f32x4*)&xgsh[buf][llo][64 + 16 * gw + lhi * 4];
      f32x4 aXN = *(const f32x4*)&xgsh[buf][llo][128 + 16 * gw + lhi * 4];
      f32x4 aHN = biasHN;
      const bf16x8 hb0 = *(const bf16x8*)&hsh[buf][llo][k0];
      const bf16x8 hb1 = *(const bf16x8*)&hsh[buf][llo][k0 + 32];
      aR  = __builtin_amdgcn_mfma_f32_16x16x32_bf16(wa[0][0], hb0, aR, 0, 0, 0);
      aR  = __builtin_amdgcn_mfma_f32_16x16x32_bf16(wa[0][1], hb1, aR, 0, 0, 0);
      aZ  = __builtin_amdgcn_mfma_f32_16x16x32_bf16(wa[1][0], hb0, aZ, 0, 0, 0);
      aZ  = __builtin_amdgcn_mfma_f32_16x16x32_bf16(wa[1][1], hb1, aZ, 0, 0, 0);
      aHN = __builtin_amdgcn_mfma_f32_16x16x32_bf16(wa[2][0], hb0, aHN, 0, 0, 0);
      aHN = __builtin_amdgcn_mfma_f32_16x16x32_bf16(wa[2][1], hb1, aHN, 0, 0, 0);
#pragma unroll
      for (int r = 0; r < 4; ++r) {
        const float rr = sigm(aR[r]);
        const float zz = sigm(aZ[r]);
        const float nn = tanhf_fast(aXN[r] + rr * aHN[r]);
        hfp[r] = (1.0f - zz) * nn + zz * hfp[r];
      }
      uint2 pk;
      pk.x = cvtpk(hfp[0], hfp[1]);
      pk.y = cvtpk(hfp[2], hfp[3]);
      *(uint2*)&hsh[buf ^ 1][llo][16 * gw + lhi * 4] = pk;
    } else {
      // convert x[t+1] (in regs) to bf16 B-frags
      union { uint32_t u[4]; bf16x8 v; } c0, c1;
      c0.u[0] = cvtpk(xq0[0], xq0[1]); c0.u[1] = cvtpk(xq0[2], xq0[3]);
      c0.u[2] = cvtpk(xq1[0], xq1[1]); c0.u[3] = cvtpk(xq1[2], xq1[3]);
      c1.u[0] = cvtpk(xq2[0], xq2[1]); c1.u[1] = cvtpk(xq2[2], xq2[3]);
      c1.u[2] = cvtpk(xq3[0], xq3[1]); c1.u[3] = cvtpk(xq3[2], xq3[3]);
      // prefetch x[t+2] (clamped; tail value unused)
      const int tn = (t + 2 < TT) ? t + 2 : TT - 1;
      const f32x4* p = (const f32x4*)(Hseq + ((size_t)tn * BB + bbase + llo) * HH + k0);
      xq0 = p[0]; xq1 = p[1]; xq2 = p[8]; xq3 = p[9];
      f32x4 cR = biasPR, cZ = biasPZ, cN = biasPN;
      cR = __builtin_amdgcn_mfma_f32_16x16x32_bf16(wa[0][0], c0.v, cR, 0, 0, 0);
      cR = __builtin_amdgcn_mfma_f32_16x16x32_bf16(wa[0][1], c1.v, cR, 0, 0, 0);
      cZ = __builtin_amdgcn_mfma_f32_16x16x32_bf16(wa[1][0], c0.v, cZ, 0, 0, 0);
      cZ = __builtin_amdgcn_mfma_f32_16x16x32_bf16(wa[1][1], c1.v, cZ, 0, 0, 0);
      cN = __builtin_amdgcn_mfma_f32_16x16x32_bf16(wa[2][0], c0.v, cN, 0, 0, 0);
      cN = __builtin_amdgcn_mfma_f32_16x16x32_bf16(wa[2][1], c1.v, cN, 0, 0, 0);
      const int ob = buf ^ 1;  // xg[t+1]
      *(f32x4*)&xgsh[ob][llo][16 * gw + lhi * 4]       = cR;
      *(f32x4*)&xgsh[ob][llo][64 + 16 * gw + lhi * 4]  = cZ;
      *(f32x4*)&xgsh[ob][llo][128 + 16 * gw + lhi * 4] = cN;
    }
    __syncthreads();
  }

  // ---- head: out[b] = h_last[b,:] . W_out + b_out ----
  if (cons) {
    float part = 0.f;
#pragma unroll
    for (int r = 0; r < 4; ++r) part += hfp[r] * W_out[16 * gw + lhi * 4 + r];
    part += __shfl_xor(part, 16);
    part += __shfl_xor(part, 32);
    if (lhi == 0) psum[gw][llo] = part;
  }
  __syncthreads();
  if (tid < BC)
    out[bbase + tid] = psum[0][tid] + psum[1][tid] + psum[2][tid] + psum[3][tid] + b_out[0];
}

extern "C" void kernel_launch(void* const* d_in, const int* in_sizes, int n_in,
                              void* d_out, int out_size, void* d_ws, size_t ws_size,
                              hipStream_t stream) {
  (void)in_sizes; (void)n_in; (void)d_ws; (void)ws_size; (void)out_size;
  const float* Hseq  = (const float*)d_in[0];
  const float* W_ih  = (const float*)d_in[1];
  const float* W_hh  = (const float*)d_in[2];
  const float* b_ih  = (const float*)d_in[3];
  const float* b_hh  = (const float*)d_in[4];
  const float* W_out = (const float*)d_in[5];
  const float* b_out = (const float*)d_in[6];
  float* out = (float*)d_out;
  gru_fused<<<BB / BC, 512, 0, stream>>>(Hseq, W_ih, W_hh, b_ih, b_hh, W_out, b_out, out);
}